// Round 6
// baseline (141.566 us; speedup 1.0000x reference)
//
#include <hip/hip_runtime.h>

#define CCH   256
#define FH    96
#define FW    96
#define HW    (FH*FW)
#define SCALE 0.0625f

#define SQMAX 7             // max row stride in quads (runtime sQ in {3,5,7})
#define PLANE (7*SQMAX*4)   // 196 floats per wave plane (7 bin-rows x <=7 quads)
#define WCH   32            // channels per wave (block = 128ch half-roi, 4 waves)

// R6 = R5's batch-sorted roi->XCD placement (proven: FETCH 100->27MB) +
// R2's separable y-fold staging (proven: DS traffic /3, conflicts 8.7M->3.2M)
// + adaptive width on the staging slots (7*cwq vs fixed 42). R5 showed HBM
// bytes are NOT the limit (27MB, 16% BW, dur unchanged) -> the DS pipe
// (~105Kcy of 147Kcy: 8 read2 + 2 write_b128 per wave-channel + 31Kcy
// conflicts, bursty) is the binding resource. y-fold: stage 7 y-interpolated
// bin-rows BR[oy][x] = 0.25*sum wy*F[y][x] (1 ds_write_b128/ch), compute =
// 2 ds_read2 + 4 FMA per output (was 8+16). R2's FETCH explosion (175MB) was
// its 4-segment loads under RANDOM placement - batch-sorting makes those L2
// hits (unique bytes/XCD unchanged). Register deep-prefetch stays DEAD
// (R1 sunk / R3 spilled 150MB scratch).
__global__ void bucket_rois(const float* __restrict__ rois, int* __restrict__ perm, int K)
{
    __shared__ int cnt[4], base[4];
    const int t = threadIdx.x;
    if (t < 4) cnt[t] = 0;
    __syncthreads();
    int b = 0, pos = 0;
    if (t < K) {
        b   = min(max((int)rois[t*5], 0), 3);
        pos = atomicAdd(&cnt[b], 1);
    }
    __syncthreads();
    if (t == 0) {
        int s = 0;
        #pragma unroll
        for (int i = 0; i < 4; ++i) { base[i] = s; s += cnt[i]; }
    }
    __syncthreads();
    if (t < K) perm[base[b] + pos] = t;
}

__global__ __launch_bounds__(256, 8)
void roialign_kernel(const float* __restrict__ feat,
                     const float* __restrict__ rois,
                     float* __restrict__ out,
                     const int* __restrict__ perm)
{
    __shared__ __align__(16) float win[4 * PLANE];
    __shared__ int   s_lo[2][14];
    __shared__ float s_wl[2][14], s_wh[2][14];

    // XCD-pair chunking (R5): xcd = blockIdx&7 (CP round-robin), pair xcd>>1
    // owns sorted-roi chunk [p*256, p*256+256) ~= one batch; half = xcd&1.
    const int xcd  = blockIdx.x & 7;
    const int j    = blockIdx.x >> 3;              // 0..255
    const int q    = ((xcd >> 1) << 8) + j;        // sorted-roi index
    const int half = xcd & 1;
    const int k    = perm ? perm[q] : q;

    const int tid  = threadIdx.x;
    const int w    = tid >> 6;
    const int ll   = tid & 63;

    // ---------- Phase A: per-roi sample coords ----------
    const float x1 = rois[k*5+1] * SCALE;
    const float y1 = rois[k*5+2] * SCALE;
    const float x2 = rois[k*5+3] * SCALE;
    const float y2 = rois[k*5+4] * SCALE;
    const int   b  = (int)rois[k*5+0];
    const float binw = fmaxf(x2 - x1, 1.0f) * (1.0f/7.0f);
    const float binh = fmaxf(y2 - y1, 1.0f) * (1.0f/7.0f);

    if (tid < 28) {
        const int   axis  = (tid >= 14) ? 1 : 0;
        const int   g     = axis ? tid - 14 : tid;
        const float start = axis ? x1 : y1;
        const float bsz   = axis ? binw : binh;
        const float offs  = (float)(g >> 1) + 0.25f + 0.5f*(float)(g & 1);
        const float coord = start + bsz * offs;
        const bool  valid = (coord >= -1.0f) && (coord <= 96.0f);
        const float cc    = fminf(fmaxf(coord, 0.0f), 95.0f);
        const float lof   = floorf(cc);
        const float frac  = cc - lof;
        // fold the 1/4 sample-mean into the y-axis (staging-side) weights
        const float v     = valid ? (axis ? 1.0f : 0.25f) : 0.0f;
        s_lo[axis][g] = (int)lof;
        s_wl[axis][g] = (1.0f - frac) * v;
        s_wh[axis][g] = frac * v;
    }
    __syncthreads();   // the ONLY barrier

    // ---------- adaptive window geometry (block-uniform) ----------
    const int col0   = s_lo[1][0] & ~3;               // 16B-aligned left edge
    const int colEnd = min(s_lo[1][13] + 1, FW-1);    // rightmost tap column
    const int width  = colEnd - col0 + 1;             // 1..24
    const int cwq    = min((width + 3) >> 2, 6);      // data quads per bin-row, 1..6
    const int sQ     = ((cwq + 1) & ~1) | 1;          // row stride quads: 3,3,5,5,7,7
    const int RS     = sQ * 4;                        // row stride floats; oy*RS mod 32
                                                      // distinct for oy=0..6 (odd sQ)
    const int nslot  = 7 * cwq;                       // staging slots, 7..42

    float* const wp = &win[w * PLANE];

    // Zero this wave's plane once (49 quads). Pad quads (q>=cwq) never
    // re-written -> stay 0 for weight-0 +1-taps (xlo==95 -> frac==0).
    if (ll < PLANE/4) *(float4*)&wp[ll*4] = make_float4(0.f, 0.f, 0.f, 0.f);

    // ---------- compute-phase constants (channel-invariant) ----------
    const bool active = ll < 49;
    const int  p  = active ? ll : 0;
    const int  oy = p / 7;
    const int  ox = p - oy*7;
    float cw0, cw1, cw2, cw3;
    int   ca0, ca1;
    {
        const int gx0 = 2*ox, gx1 = 2*ox + 1;
        const int c0  = min(s_lo[1][gx0] - col0, RS-2);  // <=4*cwq-1 provable
        const int c1  = min(s_lo[1][gx1] - col0, RS-2);
        cw0 = s_wl[1][gx0];  cw1 = s_wh[1][gx0];
        cw2 = s_wl[1][gx1];  cw3 = s_wh[1][gx1];
        ca0 = oy*RS + c0;
        ca1 = oy*RS + c1;
    }

    // ---------- staging constants: slot s = (soy, sq), nslot slots ----------
    const int  s   = min(ll, nslot - 1);
    const int  soy = s / cwq;
    const int  sq  = s - soy*cwq;
    const bool st  = ll < nslot;
    float sw0, sw1, sw2, sw3;
    int   g0, g1, g2, g3;
    {
        const int gy0 = 2*soy, gy1 = 2*soy + 1;
        const int rl0 = s_lo[0][gy0], rh0 = min(rl0 + 1, FH-1);  // rows already in [0,95]
        const int rl1 = s_lo[0][gy1], rh1 = min(rl1 + 1, FH-1);
        sw0 = s_wl[0][gy0];  sw1 = s_wh[0][gy0];
        sw2 = s_wl[0][gy1];  sw3 = s_wh[0][gy1];
        const int cq = col0 + 4*sq;        // 16B-aligned; col0+4*cwq<=96 provable
        g0 = rl0*FW + cq;  g1 = rh0*FW + cq;
        g2 = rl1*FW + cq;  g3 = rh1*FW + cq;
    }
    const int ld = soy*RS + 4*sq;          // 16B-aligned LDS slot

    const int    cb   = half*128 + w*WCH;
    const float* gch  = feat + (size_t)(b*CCH + cb) * HW;
    float*       outp = out  + ((size_t)k*CCH + cb)*49 + p;

    // ---------- 1-deep pipeline: channel c staged in regs, c+1 in flight ----------
    float4 A0, A1, A2, A3;
    if (st) {
        A0 = *(const float4*)(gch + g0);  A1 = *(const float4*)(gch + g1);
        A2 = *(const float4*)(gch + g2);  A3 = *(const float4*)(gch + g3);
    }

    for (int c = 0; c < WCH; ++c) {
        // y-fold channel c (vmcnt wait for its loads lands here), write bin-rows.
        // Within-wave DS program order: prior iteration's reads precede this write.
        if (st) {
            float4 v;
            v.x = sw0*A0.x + sw1*A1.x + sw2*A2.x + sw3*A3.x;
            v.y = sw0*A0.y + sw1*A1.y + sw2*A2.y + sw3*A3.y;
            v.z = sw0*A0.z + sw1*A1.z + sw2*A2.z + sw3*A3.z;
            v.w = sw0*A0.w + sw1*A1.w + sw2*A2.w + sw3*A3.w;
            *(float4*)&wp[ld] = v;

            if (c + 1 < WCH) {             // next channel in flight during compute
                const float* gn = gch + (size_t)(c+1)*HW;
                A0 = *(const float4*)(gn + g0);  A1 = *(const float4*)(gn + g1);
                A2 = *(const float4*)(gn + g2);  A3 = *(const float4*)(gn + g3);
            }
        }

        if (active) {
            // 2 ds_read2_b32 + 4 FMA per output (was 8 read2 + 16 FMA)
            outp[0] = cw0*wp[ca0] + cw1*wp[ca0+1]
                    + cw2*wp[ca1] + cw3*wp[ca1+1];
        }
        outp += 49;
    }
}

extern "C" void kernel_launch(void* const* d_in, const int* in_sizes, int n_in,
                              void* d_out, int out_size, void* d_ws, size_t ws_size,
                              hipStream_t stream) {
    const float* feat = (const float*)d_in[0];
    const float* rois = (const float*)d_in[1];
    float*       outp = (float*)d_out;
    const int K = in_sizes[1] / 5;   // 1024

    int* perm = nullptr;
    if (d_ws && ws_size >= (size_t)K * sizeof(int) && K <= 1024) {
        perm = (int*)d_ws;
        bucket_rois<<<1, 1024, 0, stream>>>(rois, perm, K);
    }
    roialign_kernel<<<K*2, 256, 0, stream>>>(feat, rois, outp, perm);
}

// Round 7
// 130.326 us; speedup vs baseline: 1.0862x; 1.0862x over previous
//
#include <hip/hip_runtime.h>

#define CCH   256
#define FH    96
#define FW    96
#define HW    (FH*FW)
#define SCALE 0.0625f

#define HROWS 21              // max window rows (span<=19 -> 21); hwin clamped
#define SQMAX 7               // max row stride in quads (runtime sQ in {3,5,7})
#define PLANE (HROWS*SQMAX*4) // 588 floats per wave plane (fixed alloc, runtime stride)
#define WCH   16              // channels per wave (block = 64ch quarter-roi, 4 waves)

// R7 = R4 structure FROZEN (raw adaptive window, identity mapping, 1-deep
// pipeline - best measured 60.2us/dispatch) + OVER-DECOMPOSITION: 4096 blocks
// x 64ch (quarter-roi) instead of 2048 x 128ch. Evidence: Occupancy stuck at
// 53-57% in ALL rounds while the 2048-block grid is exactly co-resident (8
// blocks/CU, zero backfill) and per-block cost varies ~2x with roi size ->
// load-imbalance tail. 16 blocks/CU scheduled onto 8 slots gives hardware
// backfill; serial per-wave loop halves (32->16). Bucket/sort kernel DROPPED:
// R5 proved FETCH (27 vs 100MB) does not move dur at this size.
// Dead ends (do not revisit): register deep-prefetch (R1 sunk/R3 spilled),
// y-fold staging (R2/R6: halves DS but doubles VMEM lane-requests -> net
// loss; request count is the stronger axis), FETCH reduction (R5: -73MB,
// dur unchanged).
// Wave-autonomous: one plane + WCH channels per wave; no barriers in the
// main loop (within-wave DS ordering is program-order). All addresses
// in-bounds by construction.
__global__ __launch_bounds__(256, 8)
void roialign_kernel(const float* __restrict__ feat,
                     const float* __restrict__ rois,
                     float* __restrict__ out)
{
    __shared__ __align__(16) float win[4 * PLANE];
    __shared__ int   s_lo[2][14];
    __shared__ float s_wl[2][14], s_wh[2][14];

    const int k    = blockIdx.x >> 2;    // identity mapping; 4 quarters per roi
    const int quar = blockIdx.x & 3;
    const int tid  = threadIdx.x;
    const int w    = tid >> 6;
    const int ll   = tid & 63;

    // ---------- Phase A: per-roi sample coords ----------
    const float x1 = rois[k*5+1] * SCALE;
    const float y1 = rois[k*5+2] * SCALE;
    const float x2 = rois[k*5+3] * SCALE;
    const float y2 = rois[k*5+4] * SCALE;
    const int   b  = (int)rois[k*5+0];
    const float binw = fmaxf(x2 - x1, 1.0f) * (1.0f/7.0f);
    const float binh = fmaxf(y2 - y1, 1.0f) * (1.0f/7.0f);

    if (tid < 28) {
        const int   axis  = (tid >= 14) ? 1 : 0;
        const int   g     = axis ? tid - 14 : tid;
        const float start = axis ? x1 : y1;
        const float bsz   = axis ? binw : binh;
        const float offs  = (float)(g >> 1) + 0.25f + 0.5f*(float)(g & 1);
        const float coord = start + bsz * offs;
        const bool  valid = (coord >= -1.0f) && (coord <= 96.0f);
        const float cc    = fminf(fmaxf(coord, 0.0f), 95.0f);
        const float lof   = floorf(cc);
        const float frac  = cc - lof;
        const float v     = valid ? 1.0f : 0.0f;
        s_lo[axis][g] = (int)lof;
        s_wl[axis][g] = (1.0f - frac) * v;
        s_wh[axis][g] = frac * v;
    }
    __syncthreads();   // the ONLY barrier

    // ---------- adaptive window geometry (block-uniform) ----------
    const int row0   = s_lo[0][0];
    const int col0   = s_lo[1][0] & ~3;               // 16B-aligned left edge
    const int colEnd = min(s_lo[1][13] + 1, FW-1);    // rightmost tap column
    const int width  = colEnd - col0 + 1;             // 1..24
    const int cwq    = min((width + 3) >> 2, 6);      // data quads per row, 1..6
    const int sQ     = ((cwq + 1) & ~1) | 1;          // row stride quads: 3,3,5,5,7,7
    const int RS     = sQ * 4;                        // row stride in floats
    int hw_          = min(s_lo[0][13] + 1, FH-1) - row0 + 1;
    const int hwin   = min(hw_, HROWS);               // defensive clamp
    const int nslot  = hwin * cwq;                    // float4 slots, <=126

    float* const wp = &win[w * PLANE];

    // Zero this wave's full plane once. Pad quads (q >= cwq) are never
    // re-written -> stay 0 for weight-0 taps.
    {
        const float4 z = make_float4(0.f, 0.f, 0.f, 0.f);
        #pragma unroll
        for (int jj = 0; jj < 3; ++jj) {
            const int qq = ll + 64*jj;
            if (qq < PLANE/4) *(float4*)&wp[qq*4] = z;
        }
    }

    // ---------- Phase B: tap addresses & pre-scaled weights (channel-invariant) ----------
    const bool active = ll < 49;
    const int  p  = active ? ll : 0;
    const int  oy = p / 7;
    const int  ox = p - oy*7;

    int   aL[4], aH[4];
    float w00[4], w01[4], w10[4], w11[4];
    #pragma unroll
    for (int sy = 0; sy < 2; ++sy) {
        const int   gy  = 2*oy + sy;
        const int   rlo = min(s_lo[0][gy] - row0,                 HROWS-1);
        const int   rhi = min(min(s_lo[0][gy]+1, FH-1) - row0,    HROWS-1);
        const float wyl = s_wl[0][gy], wyh = s_wh[0][gy];
        #pragma unroll
        for (int sx = 0; sx < 2; ++sx) {
            const int   gx  = 2*ox + sx;
            const int   clo = min(s_lo[1][gx] - col0, RS-2);   // <=4*cwq-1 provable
            const float wxl = s_wl[1][gx], wxh = s_wh[1][gx];
            const int   s   = sy*2 + sx;
            aL[s] = rlo*RS + clo;
            aH[s] = rhi*RS + clo;
            w00[s] = wyl*wxl*0.25f;  w01[s] = wyl*wxh*0.25f;   // 0.25 = sample mean
            w10[s] = wyh*wxl*0.25f;  w11[s] = wyh*wxh*0.25f;
        }
    }

    // ---------- load-slot constants: slots ll and ll+64 of nslot ----------
    const int  sl1 = ll + 64;
    const int  r0  = ll  / cwq, q0 = ll  - r0*cwq;   // runtime div, once per lane
    const int  r1  = sl1 / cwq, q1 = sl1 - r1*cwq;
    const bool L0  = ll  < nslot;
    const bool L1  = sl1 < nslot;
    // Clamped: legal addresses even for predicated-off lanes.
    const int  goff0 = min(row0 + r0, FH-1)*FW + col0 + q0*4;  // col0+4*cwq<=96
    const int  goff1 = min(row0 + r1, FH-1)*FW + col0 + q1*4;
    const int  ld0   = min(r0, HROWS-1)*RS + q0*4;
    const int  ld1   = min(r1, HROWS-1)*RS + q1*4;

    const int    cb   = quar*64 + w*WCH;             // 64ch quarter, 16ch/wave
    const float* gch  = feat + (size_t)(b*CCH + cb) * HW;
    float*       outp = out  + ((size_t)k*CCH + cb)*49 + p;

    float4 st0, st1;
    if (L0) st0 = *(const float4*)(gch + goff0);
    if (L1) st1 = *(const float4*)(gch + goff1);

    for (int c = 0; c < WCH; ++c) {
        // vmcnt wait for this channel's loads lands on these writes; within-wave
        // ds ordering guarantees prior iteration's reads see old data first.
        if (L0) *(float4*)&wp[ld0] = st0;
        if (L1) *(float4*)&wp[ld1] = st1;

        if (c + 1 < WCH) {                       // next channel in flight during compute
            const float* gn = gch + (size_t)(c+1)*HW;
            if (L0) st0 = *(const float4*)(gn + goff0);
            if (L1) st1 = *(const float4*)(gn + goff1);
        }

        if (active) {
            // 4 independent chains; wp[a], wp[a+1] adjacent -> ds_read2_b32
            float t0 = w00[0]*wp[aL[0]]   + w01[0]*wp[aL[0]+1]
                     + w10[0]*wp[aH[0]]   + w11[0]*wp[aH[0]+1];
            float t1 = w00[1]*wp[aL[1]]   + w01[1]*wp[aL[1]+1]
                     + w10[1]*wp[aH[1]]   + w11[1]*wp[aH[1]+1];
            float t2 = w00[2]*wp[aL[2]]   + w01[2]*wp[aL[2]+1]
                     + w10[2]*wp[aH[2]]   + w11[2]*wp[aH[2]+1];
            float t3 = w00[3]*wp[aL[3]]   + w01[3]*wp[aL[3]+1]
                     + w10[3]*wp[aH[3]]   + w11[3]*wp[aH[3]+1];
            outp[0] = (t0 + t1) + (t2 + t3);
        }
        outp += 49;
    }
}

extern "C" void kernel_launch(void* const* d_in, const int* in_sizes, int n_in,
                              void* d_out, int out_size, void* d_ws, size_t ws_size,
                              hipStream_t stream) {
    const float* feat = (const float*)d_in[0];
    const float* rois = (const float*)d_in[1];
    float*       outp = (float*)d_out;
    const int K = in_sizes[1] / 5;   // 1024
    roialign_kernel<<<K*4, 256, 0, stream>>>(feat, rois, outp);
}